// Round 5
// baseline (50.420 us; speedup 1.0000x reference)
//
#include <hip/hip_runtime.h>

typedef float f4 __attribute__((ext_vector_type(4)));

#define NJ 24
#define BLK 128
#define OUTW 75               // (NJ+1)*3 floats per row
#define WROWS 64              // rows per wave
#define WBUF (WROWS * OUTW)   // 4800 floats per wave region
#define CPB 2                 // chunks per block
#define CW 12                 // per-joint consts: qA[4], qB[4], xyz[3], halfnorm

// quat-chain over 24 joints for one row; stages 75 floats into wbuf row `ln`.
// All LDS deps are same-wave -> DS pipe in-order, no barriers needed.
__device__ __forceinline__ void fk_chain(const f4* __restrict__ A,
                                         const float* __restrict__ lcst,
                                         float* __restrict__ ob) {
    float th[NJ];
    #pragma unroll
    for (int j = 0; j < NJ; ++j) th[j] = A[j >> 2][j & 3];

    float Qw = 1.f, Qx = 0.f, Qy = 0.f, Qz = 0.f;
    float t0 = 0.f, t1 = 0.f, t2 = 0.f;
    ob[0] = 0.f; ob[1] = 0.f; ob[2] = 0.f;

    #pragma unroll
    for (int j = 0; j < NJ; ++j) {
        const float* cc = &lcst[j * CW];   // wave-uniform -> LDS broadcast
        float h = th[j] * cc[11];
        float s, cq;
        __sincosf(h, &s, &cq);
        float lw = cq*cc[0] + s*cc[4];
        float lx = cq*cc[1] + s*cc[5];
        float ly = cq*cc[2] + s*cc[6];
        float lz = cq*cc[3] + s*cc[7];
        float vx = cc[8], vy = cc[9], vz = cc[10];
        float px = Qy*vz - Qz*vy + Qw*vx;
        float py = Qz*vx - Qx*vz + Qw*vy;
        float pz = Qx*vy - Qy*vx + Qw*vz;
        t0 += vx + 2.0f*(Qy*pz - Qz*py);
        t1 += vy + 2.0f*(Qz*px - Qx*pz);
        t2 += vz + 2.0f*(Qx*py - Qy*px);
        float nw = Qw*lw - Qx*lx - Qy*ly - Qz*lz;
        float nx = Qw*lx + Qx*lw + Qy*lz - Qz*ly;
        float ny = Qw*ly - Qx*lz + Qy*lw + Qz*lx;
        float nz = Qw*lz + Qx*ly - Qy*lx + Qz*lw;
        Qw = nw; Qx = nx; Qy = ny; Qz = nz;
        ob[3*(j+1)+0] = t0;
        ob[3*(j+1)+1] = t1;
        ob[3*(j+1)+2] = t2;
    }
}

__global__ __launch_bounds__(BLK, 2) void fk_main_kernel(
    const float* __restrict__ ang,   // (B, 24)
    const float* __restrict__ xyz,   // (24, 3)
    const float* __restrict__ rpy,   // (24, 3)
    const float* __restrict__ axis,  // (24, 3)
    float* __restrict__ out)         // (B, 75)
{
    __shared__ float lcst[NJ * CW];
    __shared__ float buf[(BLK / 64) * WBUF];   // 2 x 19.2 KB per-wave staging

    const int tid = threadIdx.x;
    const int wv = tid >> 6, ln = tid & 63;
    float* wbuf = &buf[wv * WBUF];

    const long long chunk0 = (long long)blockIdx.x * CPB;

    // ---- preload BOTH chunks' angles at t=0 (streaming, nontemporal) ----
    const f4* g0 = (const f4*)(ang + (chunk0 * BLK + tid) * NJ);
    const f4* g1 = (const f4*)(ang + ((chunk0 + 1) * BLK + tid) * NJ);
    f4 A[6], Bv[6];
    #pragma unroll
    for (int k = 0; k < 6; ++k) A[k]  = __builtin_nontemporal_load(g0 + k);
    #pragma unroll
    for (int k = 0; k < 6; ++k) Bv[k] = __builtin_nontemporal_load(g1 + k);

    // ---- per-joint constants (lanes 0..23): quaternionized ----
    if (tid < NJ) {
        const int j = tid;
        float r = rpy[j*3+0] * 0.5f, p = rpy[j*3+1] * 0.5f, yv = rpy[j*3+2] * 0.5f;
        float sr, cr, sp, cp, sy, cy;
        __sincosf(r, &sr, &cr);
        __sincosf(p, &sp, &cp);
        __sincosf(yv, &sy, &cy);
        float qw = cr*cp*cy + sr*sp*sy;
        float qx = sr*cp*cy - cr*sp*sy;
        float qy = cr*sp*cy + sr*cp*sy;
        float qz = cr*cp*sy - sr*sp*cy;
        float ax = axis[j*3+0], ay = axis[j*3+1], az = axis[j*3+2];
        float n = sqrtf(ax*ax + ay*ay + az*az);
        float inv = 1.0f / fmaxf(n, 1e-6f);
        float ux = ax*inv, uy = ay*inv, uz = az*inv;
        float* c = &lcst[j * CW];
        c[0] = qw; c[1] = qx; c[2] = qy; c[3] = qz;
        c[4] = -(qx*ux + qy*uy + qz*uz);
        c[5] = qw*ux + qy*uz - qz*uy;
        c[6] = qw*uy + qz*ux - qx*uz;
        c[7] = qw*uz + qx*uy - qy*ux;
        c[8] = xyz[j*3+0]; c[9] = xyz[j*3+1]; c[10] = xyz[j*3+2];
        c[11] = n * 0.5f;
    }
    __syncthreads();   // only block-wide sync; everything after is wave-private

    float* ob = wbuf + ln * OUTW;          // stride 75 (odd) -> conflict-free
    const f4* lb = (const f4*)wbuf;

    // ---- chunk 0: compute + stage ----
    fk_chain(A, lcst, ob);

    // ---- dump 0 (NT stores) -- scheduler may sink these into chunk-1 compute
    {
        f4* gO = (f4*)(out + (chunk0 + 0) * (BLK * OUTW)) + wv * (WBUF / 4);
        #pragma unroll
        for (int k = 0; k < 19; ++k) {
            int i = k * 64 + ln;
            if (i < WBUF / 4) __builtin_nontemporal_store(lb[i], gO + i);
        }
    }

    // ---- chunk 1: compute + stage (WAR vs dump-0 reads: DS pipe in-order) ----
    fk_chain(Bv, lcst, ob);

    // ---- dump 1 ----
    {
        f4* gO = (f4*)(out + (chunk0 + 1) * (BLK * OUTW)) + wv * (WBUF / 4);
        #pragma unroll
        for (int k = 0; k < 19; ++k) {
            int i = k * 64 + ln;
            if (i < WBUF / 4) __builtin_nontemporal_store(lb[i], gO + i);
        }
    }
}

extern "C" void kernel_launch(void* const* d_in, const int* in_sizes, int n_in,
                              void* d_out, int out_size, void* d_ws, size_t ws_size,
                              hipStream_t stream) {
    const float* ang  = (const float*)d_in[0];
    const float* xyz  = (const float*)d_in[1];
    const float* rpy  = (const float*)d_in[2];
    const float* axis = (const float*)d_in[3];
    float* out = (float*)d_out;

    const int B = in_sizes[0] / NJ;                  // 262144
    const int grid = B / (BLK * CPB);                // 1024 = 4 blocks/CU, one round
    fk_main_kernel<<<grid, BLK, 0, stream>>>(ang, xyz, rpy, axis, out);
}

// Round 7
// 33.002 us; speedup vs baseline: 1.5278x; 1.5278x over previous
//
#include <hip/hip_runtime.h>

typedef float f4 __attribute__((ext_vector_type(4)));

#define NJ 24
#define BLK 128
#define OUTW 75               // (NJ+1)*3 floats per row
#define HROWS 32              // rows staged per pass (half-wave)
#define HBUF (HROWS * OUTW)   // 2400 floats = 9.6 KB per wave region
#define CW 12                 // per-joint consts: qA[4], qB[4], xyz[3], halfnorm

// quat-chain over 24 joints for one row; if `active`, stages 75 floats into ob.
// NOTE: ob intentionally NOT __restrict__ — it aliases the dump reads of the
// same wave buffer; restrict here licenses a WAR reorder (R6 failure).
__device__ __forceinline__ void fk_chain(const f4* __restrict__ A,
                                         const float* __restrict__ lcst,
                                         float* ob, bool active) {
    float Qw = 1.f, Qx = 0.f, Qy = 0.f, Qz = 0.f;
    float t0 = 0.f, t1 = 0.f, t2 = 0.f;
    if (active) { ob[0] = 0.f; ob[1] = 0.f; ob[2] = 0.f; }

    #pragma unroll
    for (int j = 0; j < NJ; ++j) {
        const float* cc = &lcst[j * CW];   // wave-uniform -> LDS broadcast
        float h = A[j >> 2][j & 3] * cc[11];
        float s, cq;
        __sincosf(h, &s, &cq);
        float lw = cq*cc[0] + s*cc[4];
        float lx = cq*cc[1] + s*cc[5];
        float ly = cq*cc[2] + s*cc[6];
        float lz = cq*cc[3] + s*cc[7];
        float vx = cc[8], vy = cc[9], vz = cc[10];
        float px = Qy*vz - Qz*vy + Qw*vx;
        float py = Qz*vx - Qx*vz + Qw*vy;
        float pz = Qx*vy - Qy*vx + Qw*vz;
        t0 += vx + 2.0f*(Qy*pz - Qz*py);
        t1 += vy + 2.0f*(Qz*px - Qx*pz);
        t2 += vz + 2.0f*(Qx*py - Qy*px);
        float nw = Qw*lw - Qx*lx - Qy*ly - Qz*lz;
        float nx = Qw*lx + Qx*lw + Qy*lz - Qz*ly;
        float ny = Qw*ly - Qx*lz + Qy*lw + Qz*lx;
        float nz = Qw*lz + Qx*ly - Qy*lx + Qz*lw;
        Qw = nw; Qx = nx; Qy = ny; Qz = nz;
        if (active) {
            ob[3*(j+1)+0] = t0;
            ob[3*(j+1)+1] = t1;
            ob[3*(j+1)+2] = t2;
        }
    }
}

__global__ __launch_bounds__(BLK, 4) void fk_main_kernel(
    const float* __restrict__ ang,   // (B, 24)
    const float* __restrict__ xyz,   // (24, 3)
    const float* __restrict__ rpy,   // (24, 3)
    const float* __restrict__ axis,  // (24, 3)
    float* __restrict__ out)         // (B, 75)
{
    __shared__ float lcst[NJ * CW];            // 1152 B
    __shared__ float buf[(BLK / 64) * HBUF];   // 2 x 9.6 KB per-wave half-regions

    const int tid = threadIdx.x;
    const int wv = tid >> 6, ln = tid & 63;
    float* wbuf = &buf[wv * HBUF];

    // ---- my row's 24 angles via 6x float4 (cached; L2 line reuse) ----
    const f4* gA = (const f4*)(ang + ((long long)blockIdx.x * BLK + tid) * NJ);
    f4 A[6];
    #pragma unroll
    for (int k = 0; k < 6; ++k) A[k] = gA[k];

    // ---- per-joint constants (lanes 0..23): quaternionized ----
    if (tid < NJ) {
        const int j = tid;
        float r = rpy[j*3+0] * 0.5f, p = rpy[j*3+1] * 0.5f, yv = rpy[j*3+2] * 0.5f;
        float sr, cr, sp, cp, sy, cy;
        __sincosf(r, &sr, &cr);
        __sincosf(p, &sp, &cp);
        __sincosf(yv, &sy, &cy);
        float qw = cr*cp*cy + sr*sp*sy;
        float qx = sr*cp*cy - cr*sp*sy;
        float qy = cr*sp*cy + sr*cp*sy;
        float qz = cr*cp*sy - sr*sp*cy;
        float ax = axis[j*3+0], ay = axis[j*3+1], az = axis[j*3+2];
        float n = sqrtf(ax*ax + ay*ay + az*az);
        float inv = 1.0f / fmaxf(n, 1e-6f);
        float ux = ax*inv, uy = ay*inv, uz = az*inv;
        float* c = &lcst[j * CW];
        c[0] = qw; c[1] = qx; c[2] = qy; c[3] = qz;
        c[4] = -(qx*ux + qy*uy + qz*uz);
        c[5] = qw*ux + qy*uz - qz*uy;
        c[6] = qw*uy + qz*ux - qx*uz;
        c[7] = qw*uz + qx*uy - qy*ux;
        c[8] = xyz[j*3+0]; c[9] = xyz[j*3+1]; c[10] = xyz[j*3+2];
        c[11] = n * 0.5f;
    }
    __syncthreads();   // only block-wide sync; everything after is wave-private

    // global base for this wave: block covers 128 rows, wave covers 64
    float* gbase = out + (long long)blockIdx.x * (BLK * OUTW) + wv * (64 * OUTW);

    // ---- pass 0: all lanes run chain, lanes 0..31 stage rows 0..31 ----
    fk_chain(A, lcst, wbuf + (ln & 31) * OUTW, ln < HROWS);

    asm volatile("" ::: "memory");   // stage-writes -> dump-reads order (RAW)

    {   // dump half 0: 2400 floats contiguous, full-line f4 stores
        const f4* lb = (const f4*)wbuf;
        f4* gO = (f4*)gbase;
        #pragma unroll
        for (int k = 0; k < 10; ++k) {
            int i = k * 64 + ln;
            if (i < HBUF / 4) gO[i] = lb[i];
        }
    }

    asm volatile("" ::: "memory");   // dump-reads -> pass-1 stage-writes (WAR)

    // ---- pass 1: recompute, lanes 32..63 stage rows 32..63 ----
    // (DS pipe is in-order per wave; fences above keep compiler program order.
    //  Dump-0 global stores drain asynchronously under this compute.)
    fk_chain(A, lcst, wbuf + (ln & 31) * OUTW, ln >= HROWS);

    asm volatile("" ::: "memory");   // stage-writes -> dump-reads order (RAW)

    {   // dump half 1
        const f4* lb = (const f4*)wbuf;
        f4* gO = (f4*)(gbase + HBUF);
        #pragma unroll
        for (int k = 0; k < 10; ++k) {
            int i = k * 64 + ln;
            if (i < HBUF / 4) gO[i] = lb[i];
        }
    }
}

extern "C" void kernel_launch(void* const* d_in, const int* in_sizes, int n_in,
                              void* d_out, int out_size, void* d_ws, size_t ws_size,
                              hipStream_t stream) {
    const float* ang  = (const float*)d_in[0];
    const float* xyz  = (const float*)d_in[1];
    const float* rpy  = (const float*)d_in[2];
    const float* axis = (const float*)d_in[3];
    float* out = (float*)d_out;

    const int B = in_sizes[0] / NJ;          // 262144
    const int grid = B / BLK;                // 2048 = 8 blocks/CU, one round
    fk_main_kernel<<<grid, BLK, 0, stream>>>(ang, xyz, rpy, axis, out);
}